// Round 1
// baseline (181.089 us; speedup 1.0000x reference)
//
#include <hip/hip_runtime.h>
#include <hip/hip_bf16.h>
#include <stdint.h>

// Problem constants (from reference): B=4, deep_C=256, shallow_C=64, H=W=64
// N = 4096, qk_C = 16.
#define LOG2E 1.44269504088896340736f

typedef __bf16 bf16x8 __attribute__((ext_vector_type(8)));
typedef float  f32x16 __attribute__((ext_vector_type(16)));

__device__ __forceinline__ uint32_t pack_bf2(float a, float b) {
    __bf16 ba = (__bf16)a;  // RNE
    __bf16 bb = (__bf16)b;
    uint16_t ua = __builtin_bit_cast(uint16_t, ba);
    uint16_t ub = __builtin_bit_cast(uint16_t, bb);
    return (uint32_t)ua | ((uint32_t)ub << 16);
}

// ---------------- Prepass 1: q/k 1x1-conv + hi/lo bf16 split -------------
// Qb/Kb rows: [b][n][32 bf16] = [hi c=0..15 | lo c=0..15]  (64 B per row)
__global__ void qk_prepass(const float* __restrict__ shallow,
                           const float* __restrict__ Wq, const float* __restrict__ bq,
                           const float* __restrict__ Wk, const float* __restrict__ bk,
                           uint16_t* __restrict__ Qb, uint16_t* __restrict__ Kb) {
    int gid = blockIdx.x * 256 + threadIdx.x;   // 0..16383 = b*4096+n
    int b = gid >> 12;
    int n = gid & 4095;
    const float* sp = shallow + (size_t)b * 64 * 4096 + n;
    float q[16], k[16];
#pragma unroll
    for (int o = 0; o < 16; ++o) { q[o] = bq[o]; k[o] = bk[o]; }
    for (int c = 0; c < 64; ++c) {
        float s = sp[(size_t)c * 4096];
#pragma unroll
        for (int o = 0; o < 16; ++o) {
            q[o] = fmaf(Wq[o * 64 + c], s, q[o]);
            k[o] = fmaf(Wk[o * 64 + c], s, k[o]);
        }
    }
    uint16_t* qr = Qb + (size_t)gid * 32;
    uint16_t* kr = Kb + (size_t)gid * 32;
#pragma unroll
    for (int o = 0; o < 16; ++o) {
        __bf16 qh = (__bf16)q[o]; float qhf = (float)qh;
        __bf16 ql = (__bf16)(q[o] - qhf);
        qr[o]      = __builtin_bit_cast(uint16_t, qh);
        qr[16 + o] = __builtin_bit_cast(uint16_t, ql);
        __bf16 kh = (__bf16)k[o]; float khf = (float)kh;
        __bf16 kl = (__bf16)(k[o] - khf);
        kr[o]      = __builtin_bit_cast(uint16_t, kh);
        kr[16 + o] = __builtin_bit_cast(uint16_t, kl);
    }
}

// ---------------- Prepass 2: deep fp32 -> bf16 V copy --------------------
__global__ void vconv(const float* __restrict__ deep, uint16_t* __restrict__ vb) {
    int gid = blockIdx.x * 256 + threadIdx.x;   // 0..524287, 8 elems each
    const float4* dp = (const float4*)deep + (size_t)gid * 2;
    float4 f0 = dp[0], f1 = dp[1];
    uint32_t u0 = pack_bf2(f0.x, f0.y);
    uint32_t u1 = pack_bf2(f0.z, f0.w);
    uint32_t u2 = pack_bf2(f1.x, f1.y);
    uint32_t u3 = pack_bf2(f1.z, f1.w);
    ((uint4*)vb)[gid] = make_uint4(u0, u1, u2, u3);
}

// ---------------- Main fused flash-attention kernel ----------------------
// Grid: 256 blocks x 512 threads. Block = (b, 64-query tile).
// Wave w: qw = w>>2 (2 halves of 32 queries), cw = w&3 (64 channels each).
// Computes out^T[c,q] tiles with mfma_f32_32x32x16_bf16:
//   energy^T = K·Q (split hi/lo), online softmax per lane-column, P relayout
//   in-register via shfl_xor(32), PV: acc = V_tile · P^T.
__global__ void __launch_bounds__(512) attn_main(
    const uint16_t* __restrict__ Qb, const uint16_t* __restrict__ Kb,
    const uint16_t* __restrict__ Vb, const float* __restrict__ deep,
    const float* __restrict__ gamma, float* __restrict__ out) {
    const int lane = threadIdx.x & 63;
    const int w    = threadIdx.x >> 6;
    const int qw   = w >> 2;
    const int cw   = w & 3;
    const int col  = lane & 31;   // query column (QK C-layout) / c-row (V A-layout)
    const int h1   = lane >> 5;

    // XCD-locality swizzle: assume xcd = blockIdx.x % 8; give each XCD one b.
    const int bid = blockIdx.x;
    const int xcd = bid & 7;
    const int b   = xcd >> 1;
    const int qt  = ((bid >> 3) << 1) + (xcd & 1);   // 0..63
    const int n0q = qt * 64 + qw * 32;

    // Hoisted Q B-operand frags (col=query, k-slot (h1,e) = c channel 8*h1+e)
    const uint16_t* qrow = Qb + ((size_t)(b * 4096 + n0q + col)) * 32;
    bf16x8 bqh = __builtin_bit_cast(bf16x8, *(const uint4*)(qrow + h1 * 8));
    bf16x8 bql = __builtin_bit_cast(bf16x8, *(const uint4*)(qrow + 16 + h1 * 8));

    const int ct0 = cw * 2, ct1 = cw * 2 + 1;        // two 32-channel tiles
    const uint16_t* vrow0 = Vb + ((size_t)(b * 256 + ct0 * 32 + col)) * 4096;
    const uint16_t* vrow1 = Vb + ((size_t)(b * 256 + ct1 * 32 + col)) * 4096;

    f32x16 acc0 = {0,0,0,0,0,0,0,0,0,0,0,0,0,0,0,0};
    f32x16 acc1 = {0,0,0,0,0,0,0,0,0,0,0,0,0,0,0,0};
    float m2 = -INFINITY;   // running max, log2 domain
    float l  = 0.0f;

    // K frag prefetch (row j = col)
    const uint16_t* krow = Kb + ((size_t)(b * 4096 + 0 + col)) * 32;
    uint4 ukh = *(const uint4*)(krow + h1 * 8);
    uint4 ukl = *(const uint4*)(krow + 16 + h1 * 8);

    for (int it = 0; it < 128; ++it) {
        const int n0 = it * 32;
        // V A-operand loads (row = c, k-slot (h1,e) = key n0+8*h1+e / +16)
        uint4 uav00 = *(const uint4*)(vrow0 + n0 + h1 * 8);
        uint4 uav01 = *(const uint4*)(vrow0 + n0 + 16 + h1 * 8);
        uint4 uav10 = *(const uint4*)(vrow1 + n0 + h1 * 8);
        uint4 uav11 = *(const uint4*)(vrow1 + n0 + 16 + h1 * 8);
        // next-iter K prefetch
        const int n0n = (it < 127) ? n0 + 32 : n0;
        const uint16_t* krn = Kb + ((size_t)(b * 4096 + n0n + col)) * 32;
        uint4 ukhn = *(const uint4*)(krn + h1 * 8);
        uint4 ukln = *(const uint4*)(krn + 16 + h1 * 8);

        // energy^T = Kh·Qh + Kl·Qh + Kh·Ql  (fp32-accurate split product)
        bf16x8 akh = __builtin_bit_cast(bf16x8, ukh);
        bf16x8 akl = __builtin_bit_cast(bf16x8, ukl);
        f32x16 e = {0,0,0,0,0,0,0,0,0,0,0,0,0,0,0,0};
        e = __builtin_amdgcn_mfma_f32_32x32x16_bf16(akh, bqh, e, 0, 0, 0);
        e = __builtin_amdgcn_mfma_f32_32x32x16_bf16(akl, bqh, e, 0, 0, 0);
        e = __builtin_amdgcn_mfma_f32_32x32x16_bf16(akh, bql, e, 0, 0, 0);

        // ---- online softmax (per lane col = one query) ----
        float tmax = e[0];
#pragma unroll
        for (int r = 1; r < 16; ++r) tmax = fmaxf(tmax, e[r]);
        tmax = fmaxf(tmax, __shfl_xor(tmax, 32, 64));
        float t2 = tmax * LOG2E;
        if (__any(t2 > m2)) {            // defer rescale unless max grew
            float nm2 = fmaxf(m2, t2);
            float sc  = exp2f(m2 - nm2);
#pragma unroll
            for (int r = 0; r < 16; ++r) { acc0[r] *= sc; acc1[r] *= sc; }
            l *= sc;
            m2 = nm2;
        }
        float p[16];
        float ls = 0.0f;
#pragma unroll
        for (int r = 0; r < 16; ++r) {
            p[r] = exp2f(fmaf(e[r], LOG2E, -m2));
            ls += p[r];
        }
        ls += __shfl_xor(ls, 32, 64);
        l += ls;

        // ---- P -> B-operand relayout (C-layout key = (r&3)+8*(r>>2)+4*h1) ----
        uint32_t pk0 = pack_bf2(p[0],  p[1]),  pk1 = pack_bf2(p[2],  p[3]);
        uint32_t pk2 = pack_bf2(p[4],  p[5]),  pk3 = pack_bf2(p[6],  p[7]);
        uint32_t pk4 = pack_bf2(p[8],  p[9]),  pk5 = pack_bf2(p[10], p[11]);
        uint32_t pk6 = pack_bf2(p[12], p[13]), pk7 = pack_bf2(p[14], p[15]);
        // frag0 = keys 0..15
        uint32_t own_a = h1 ? pk2 : pk0, own_b = h1 ? pk3 : pk1;
        uint32_t cr_a  = h1 ? pk0 : pk2, cr_b  = h1 ? pk1 : pk3;
        uint32_t rc_a  = __shfl_xor(cr_a, 32, 64), rc_b = __shfl_xor(cr_b, 32, 64);
        uint4 f0u = make_uint4(h1 ? rc_a : own_a, h1 ? rc_b : own_b,
                               h1 ? own_a : rc_a, h1 ? own_b : rc_b);
        // frag1 = keys 16..31
        uint32_t own_a1 = h1 ? pk6 : pk4, own_b1 = h1 ? pk7 : pk5;
        uint32_t cr_a1  = h1 ? pk4 : pk6, cr_b1  = h1 ? pk5 : pk7;
        uint32_t rc_a1  = __shfl_xor(cr_a1, 32, 64), rc_b1 = __shfl_xor(cr_b1, 32, 64);
        uint4 f1u = make_uint4(h1 ? rc_a1 : own_a1, h1 ? rc_b1 : own_b1,
                               h1 ? own_a1 : rc_a1, h1 ? own_b1 : rc_b1);
        bf16x8 PB0 = __builtin_bit_cast(bf16x8, f0u);
        bf16x8 PB1 = __builtin_bit_cast(bf16x8, f1u);

        // ---- PV: acc(out^T tile) += V_tile · P^T ----
        acc0 = __builtin_amdgcn_mfma_f32_32x32x16_bf16(__builtin_bit_cast(bf16x8, uav00), PB0, acc0, 0, 0, 0);
        acc0 = __builtin_amdgcn_mfma_f32_32x32x16_bf16(__builtin_bit_cast(bf16x8, uav01), PB1, acc0, 0, 0, 0);
        acc1 = __builtin_amdgcn_mfma_f32_32x32x16_bf16(__builtin_bit_cast(bf16x8, uav10), PB0, acc1, 0, 0, 0);
        acc1 = __builtin_amdgcn_mfma_f32_32x32x16_bf16(__builtin_bit_cast(bf16x8, uav11), PB1, acc1, 0, 0, 0);

        ukh = ukhn; ukl = ukln;
    }

    // ---- epilogue: out = gamma * acc/l + deep ----
    const float g   = gamma[0];
    const float rin = 1.0f / l;
    const float gr  = g * rin;
    const int n = n0q + col;
#pragma unroll
    for (int r = 0; r < 16; ++r) {
        const int crow = (r & 3) + 8 * (r >> 2) + 4 * h1;
        size_t i0 = ((size_t)(b * 256 + ct0 * 32 + crow)) * 4096 + n;
        out[i0] = fmaf(gr, acc0[r], deep[i0]);
        size_t i1 = ((size_t)(b * 256 + ct1 * 32 + crow)) * 4096 + n;
        out[i1] = fmaf(gr, acc1[r], deep[i1]);
    }
}

extern "C" void kernel_launch(void* const* d_in, const int* in_sizes, int n_in,
                              void* d_out, int out_size, void* d_ws, size_t ws_size,
                              hipStream_t stream) {
    const float* deep    = (const float*)d_in[0];
    const float* shallow = (const float*)d_in[1];
    const float* Wq      = (const float*)d_in[2];
    const float* bq      = (const float*)d_in[3];
    const float* Wk      = (const float*)d_in[4];
    const float* bk      = (const float*)d_in[5];
    const float* gamma   = (const float*)d_in[6];
    float* out = (float*)d_out;

    // ws layout: Vb bf16 copy of deep (8 MiB) | Qb (1 MiB) | Kb (1 MiB)
    uint16_t* Vb = (uint16_t*)d_ws;
    uint16_t* Qb = (uint16_t*)((char*)d_ws + (size_t)8 * 1024 * 1024);
    uint16_t* Kb = (uint16_t*)((char*)d_ws + (size_t)9 * 1024 * 1024);

    hipLaunchKernelGGL(vconv, dim3(2048), dim3(256), 0, stream, deep, Vb);
    hipLaunchKernelGGL(qk_prepass, dim3(64), dim3(256), 0, stream,
                       shallow, Wq, bq, Wk, bk, Qb, Kb);
    hipLaunchKernelGGL(attn_main, dim3(256), dim3(512), 0, stream,
                       Qb, Kb, Vb, deep, gamma, out);
}

// Round 2
// 172.923 us; speedup vs baseline: 1.0472x; 1.0472x over previous
//
#include <hip/hip_runtime.h>
#include <hip/hip_bf16.h>
#include <stdint.h>

// Problem constants: B=4, deep_C=256, shallow_C=64, H=W=64, N=4096, qk_C=16.
#define LOG2E 1.44269504088896340736f

typedef __bf16 bf16x8 __attribute__((ext_vector_type(8)));
typedef float  f32x16 __attribute__((ext_vector_type(16)));

__device__ __forceinline__ uint32_t pack_bf2(float a, float b) {
    __bf16 ba = (__bf16)a;  // RNE
    __bf16 bb = (__bf16)b;
    uint16_t ua = __builtin_bit_cast(uint16_t, ba);
    uint16_t ub = __builtin_bit_cast(uint16_t, bb);
    return (uint32_t)ua | ((uint32_t)ub << 16);
}

// ---------------- Prepass 1: q/k 1x1-conv + hi/lo bf16 split -------------
// Qb/Kb rows: [b][n][32 bf16] = [hi c=0..15 | lo c=0..15]  (64 B per row)
__global__ void qk_prepass(const float* __restrict__ shallow,
                           const float* __restrict__ Wq, const float* __restrict__ bq,
                           const float* __restrict__ Wk, const float* __restrict__ bk,
                           uint16_t* __restrict__ Qb, uint16_t* __restrict__ Kb) {
    int gid = blockIdx.x * 256 + threadIdx.x;   // 0..16383 = b*4096+n
    int b = gid >> 12;
    int n = gid & 4095;
    const float* sp = shallow + (size_t)b * 64 * 4096 + n;
    float q[16], k[16];
#pragma unroll
    for (int o = 0; o < 16; ++o) { q[o] = bq[o]; k[o] = bk[o]; }
    for (int c = 0; c < 64; ++c) {
        float s = sp[(size_t)c * 4096];
#pragma unroll
        for (int o = 0; o < 16; ++o) {
            q[o] = fmaf(Wq[o * 64 + c], s, q[o]);
            k[o] = fmaf(Wk[o * 64 + c], s, k[o]);
        }
    }
    uint16_t* qr = Qb + (size_t)gid * 32;
    uint16_t* kr = Kb + (size_t)gid * 32;
#pragma unroll
    for (int o = 0; o < 16; ++o) {
        __bf16 qh = (__bf16)q[o]; float qhf = (float)qh;
        __bf16 ql = (__bf16)(q[o] - qhf);
        qr[o]      = __builtin_bit_cast(uint16_t, qh);
        qr[16 + o] = __builtin_bit_cast(uint16_t, ql);
        __bf16 kh = (__bf16)k[o]; float khf = (float)kh;
        __bf16 kl = (__bf16)(k[o] - khf);
        kr[o]      = __builtin_bit_cast(uint16_t, kh);
        kr[16 + o] = __builtin_bit_cast(uint16_t, kl);
    }
}

// ---------------- Prepass 2: deep fp32 -> bf16 V copy --------------------
__global__ void vconv(const float* __restrict__ deep, uint16_t* __restrict__ vb) {
    int gid = blockIdx.x * 256 + threadIdx.x;   // 0..524287, 8 elems each
    const float4* dp = (const float4*)deep + (size_t)gid * 2;
    float4 f0 = dp[0], f1 = dp[1];
    uint32_t u0 = pack_bf2(f0.x, f0.y);
    uint32_t u1 = pack_bf2(f0.z, f0.w);
    uint32_t u2 = pack_bf2(f1.x, f1.y);
    uint32_t u3 = pack_bf2(f1.z, f1.w);
    ((uint4*)vb)[gid] = make_uint4(u0, u1, u2, u3);
}

// ---------------- Main fused flash-attention kernel ----------------------
// Grid: 512 blocks x 512 threads. Block = (b, 32-query tile), all 256 chans.
// Superstep = 256 keys. Phase 1: wave w computes QK^T+softmax for its own
// 32-key slice (dup=1), P packed to MFMA B-frags, shared via LDS. Phase 2:
// wave w owns 32 channels, consumes all 16 P frags (256 keys).
__global__ void __launch_bounds__(512, 4) attn_main(
    const uint16_t* __restrict__ Qb, const uint16_t* __restrict__ Kb,
    const uint16_t* __restrict__ Vb, const float* __restrict__ deep,
    const float* __restrict__ gamma, float* __restrict__ out) {
    const int lane = threadIdx.x & 63;
    const int w    = threadIdx.x >> 6;   // phase1: key-slice; phase2: chan-tile
    const int col  = lane & 31;          // query col (QK C, PV C) / chan row (V A)
    const int h1   = lane >> 5;

    // XCD-locality: xcd = bid % 8; one batch per XCD pair.
    const int bid = blockIdx.x;
    const int xcd = bid & 7;
    const int b   = xcd >> 1;
    const int qt  = ((bid >> 3) << 1) + (xcd & 1);   // 0..127
    const int n0q = qt * 32;

    __shared__ uint4 Pl[2][16][64];   // parity, key-frag(16 keys), lane  = 32 KB
    __shared__ float Tm[2][8][32];    // parity, kt-wave, query   (log2 domain)
    __shared__ float Ls[2][8][32];

    // Hoisted Q B-frags (col=query, k-slot (h1,e) = channel 8*h1+e)
    const uint16_t* qrow = Qb + ((size_t)(b * 4096 + n0q + col)) * 32;
    bf16x8 bqh = __builtin_bit_cast(bf16x8, *(const uint4*)(qrow + h1 * 8));
    bf16x8 bql = __builtin_bit_cast(bf16x8, *(const uint4*)(qrow + 16 + h1 * 8));

    // V rows for this wave's channel tile (A-operand: row=channel=col)
    const uint16_t* vrow = Vb + ((size_t)(b * 256 + w * 32 + col)) * 4096;

    f32x16 acc = {0,0,0,0,0,0,0,0,0,0,0,0,0,0,0,0};
    float m2 = -INFINITY;   // running max, log2 domain (per query=col)
    float l  = 0.0f;

    // K A-frag prefetch for superstep 0 (this wave's key slice w)
    const uint16_t* krow0 = Kb + ((size_t)(b * 4096 + w * 32 + col)) * 32;
    uint4 ukh = *(const uint4*)(krow0 + h1 * 8);
    uint4 ukl = *(const uint4*)(krow0 + 16 + h1 * 8);

    for (int ss = 0; ss < 16; ++ss) {
        const int n0  = ss * 256;
        const int par = ss & 1;

        // ---- phase 1: energy^T = Kh·Qh + Kl·Qh + Kh·Ql for 32 keys ----
        bf16x8 akh = __builtin_bit_cast(bf16x8, ukh);
        bf16x8 akl = __builtin_bit_cast(bf16x8, ukl);
        f32x16 e = {0,0,0,0,0,0,0,0,0,0,0,0,0,0,0,0};
        e = __builtin_amdgcn_mfma_f32_32x32x16_bf16(akh, bqh, e, 0, 0, 0);
        e = __builtin_amdgcn_mfma_f32_32x32x16_bf16(akl, bqh, e, 0, 0, 0);
        e = __builtin_amdgcn_mfma_f32_32x32x16_bf16(akh, bql, e, 0, 0, 0);

        // tree-max over the 16 rows this lane holds
        float t8[8];
#pragma unroll
        for (int i = 0; i < 8; ++i) t8[i] = fmaxf(e[2 * i], e[2 * i + 1]);
        float t4a = fmaxf(t8[0], t8[1]), t4b = fmaxf(t8[2], t8[3]);
        float t4c = fmaxf(t8[4], t8[5]), t4d = fmaxf(t8[6], t8[7]);
        float tmax = fmaxf(fmaxf(t4a, t4b), fmaxf(t4c, t4d));
        tmax = fmaxf(tmax, __shfl_xor(tmax, 32, 64));
        if (lane < 32) Tm[par][w][col] = tmax * LOG2E;
        __syncthreads();   // barrier 1

        // cross-wave max (per query)
        float M = m2;
#pragma unroll
        for (int j = 0; j < 8; ++j) M = fmaxf(M, Tm[par][j][col]);
        float sc = exp2f(m2 - M);    // old-max rescale factor (0 on first ss)
        m2 = M;

        float p[16];
        float ls = 0.0f;
#pragma unroll
        for (int r = 0; r < 16; ++r) {
            p[r] = exp2f(fmaf(e[r], LOG2E, -M));
            ls += p[r];
        }
        ls += __shfl_xor(ls, 32, 64);
        if (lane < 32) Ls[par][w][col] = ls;

        // pack P -> B-frags (C-layout key = (r&3)+8*(r>>2)+4*h1)
        uint32_t pk0 = pack_bf2(p[0],  p[1]),  pk1 = pack_bf2(p[2],  p[3]);
        uint32_t pk2 = pack_bf2(p[4],  p[5]),  pk3 = pack_bf2(p[6],  p[7]);
        uint32_t pk4 = pack_bf2(p[8],  p[9]),  pk5 = pack_bf2(p[10], p[11]);
        uint32_t pk6 = pack_bf2(p[12], p[13]), pk7 = pack_bf2(p[14], p[15]);
        uint32_t own_a = h1 ? pk2 : pk0, own_b = h1 ? pk3 : pk1;
        uint32_t cr_a  = h1 ? pk0 : pk2, cr_b  = h1 ? pk1 : pk3;
        uint32_t rc_a  = __shfl_xor(cr_a, 32, 64), rc_b = __shfl_xor(cr_b, 32, 64);
        uint4 f0u = make_uint4(h1 ? rc_a : own_a, h1 ? rc_b : own_b,
                               h1 ? own_a : rc_a, h1 ? own_b : rc_b);
        uint32_t own_a1 = h1 ? pk6 : pk4, own_b1 = h1 ? pk7 : pk5;
        uint32_t cr_a1  = h1 ? pk4 : pk6, cr_b1  = h1 ? pk5 : pk7;
        uint32_t rc_a1  = __shfl_xor(cr_a1, 32, 64), rc_b1 = __shfl_xor(cr_b1, 32, 64);
        uint4 f1u = make_uint4(h1 ? rc_a1 : own_a1, h1 ? rc_b1 : own_b1,
                               h1 ? own_a1 : rc_a1, h1 ? own_b1 : rc_b1);
        Pl[par][w * 2 + 0][lane] = f0u;
        Pl[par][w * 2 + 1][lane] = f1u;
        __syncthreads();   // barrier 2

        // K prefetch for next superstep (after barrier so its latency hides
        // under PV instead of stalling the barrier's vmcnt drain)
        const int ssn = (ss < 15) ? ss + 1 : ss;
        const uint16_t* krn = Kb + ((size_t)(b * 4096 + ssn * 256 + w * 32 + col)) * 32;
        ukh = *(const uint4*)(krn + h1 * 8);
        ukl = *(const uint4*)(krn + 16 + h1 * 8);

        // ---- phase 2: l update, acc rescale, PV over 256 keys ----
        float lsum = 0.0f;
#pragma unroll
        for (int j = 0; j < 8; ++j) lsum += Ls[par][j][col];
        l = l * sc + lsum;
#pragma unroll
        for (int r = 0; r < 16; ++r) acc[r] *= sc;

#pragma unroll
        for (int f = 0; f < 16; ++f) {
            uint4 pb = Pl[par][f][lane];
            uint4 av = *(const uint4*)(vrow + n0 + f * 16 + h1 * 8);
            acc = __builtin_amdgcn_mfma_f32_32x32x16_bf16(
                __builtin_bit_cast(bf16x8, av),
                __builtin_bit_cast(bf16x8, pb), acc, 0, 0, 0);
        }
    }

    // ---- epilogue: out = gamma * acc/l + deep ----
    const float g  = gamma[0];
    const float gr = g / l;
    const int n = n0q + col;
#pragma unroll
    for (int r = 0; r < 16; ++r) {
        const int crow = (r & 3) + 8 * (r >> 2) + 4 * h1;
        size_t i0 = ((size_t)(b * 256 + w * 32 + crow)) * 4096 + n;
        out[i0] = fmaf(gr, acc[r], deep[i0]);
    }
}

extern "C" void kernel_launch(void* const* d_in, const int* in_sizes, int n_in,
                              void* d_out, int out_size, void* d_ws, size_t ws_size,
                              hipStream_t stream) {
    const float* deep    = (const float*)d_in[0];
    const float* shallow = (const float*)d_in[1];
    const float* Wq      = (const float*)d_in[2];
    const float* bq      = (const float*)d_in[3];
    const float* Wk      = (const float*)d_in[4];
    const float* bk      = (const float*)d_in[5];
    const float* gamma   = (const float*)d_in[6];
    float* out = (float*)d_out;

    // ws layout: Vb bf16 copy of deep (8 MiB) | Qb (1 MiB) | Kb (1 MiB)
    uint16_t* Vb = (uint16_t*)d_ws;
    uint16_t* Qb = (uint16_t*)((char*)d_ws + (size_t)8 * 1024 * 1024);
    uint16_t* Kb = (uint16_t*)((char*)d_ws + (size_t)9 * 1024 * 1024);

    hipLaunchKernelGGL(vconv, dim3(2048), dim3(256), 0, stream, deep, Vb);
    hipLaunchKernelGGL(qk_prepass, dim3(64), dim3(256), 0, stream,
                       shallow, Wq, bq, Wk, bk, Qb, Kb);
    hipLaunchKernelGGL(attn_main, dim3(512), dim3(512), 0, stream,
                       Qb, Kb, Vb, deep, gamma, out);
}

// Round 3
// 105.839 us; speedup vs baseline: 1.7110x; 1.6338x over previous
//
#include <hip/hip_runtime.h>
#include <hip/hip_bf16.h>
#include <stdint.h>

// Problem constants: B=4, deep_C=256, shallow_C=64, H=W=64, N=4096, qk_C=16.
#define LOG2E 1.44269504088896340736f

typedef __bf16 bf16x8 __attribute__((ext_vector_type(8)));
typedef float  f32x16 __attribute__((ext_vector_type(16)));

__device__ __forceinline__ uint32_t pack_bf2(float a, float b) {
    __bf16 ba = (__bf16)a;  // RNE
    __bf16 bb = (__bf16)b;
    uint16_t ua = __builtin_bit_cast(uint16_t, ba);
    uint16_t ub = __builtin_bit_cast(uint16_t, bb);
    return (uint32_t)ua | ((uint32_t)ub << 16);
}

// ---------------- Prepass 1: q/k 1x1-conv, K pre-swizzled ----------------
// Qb rows: [b][n][32 bf16] = [hi c0..15 | lo c0..15] (64 B/row, per-wave 1x)
// Kb2 units (16 B = 8 bf16): addr_u16 = b*131072 + (n>>5)*1024 + s*512
//   + (h1*32 + (n&31))*8   where s=0 hi / 1 lo, h1 = chan-half.
// In attn phase 1 a wave's 64 lanes then read one contiguous 1 KB chunk.
__global__ void qk_prepass(const float* __restrict__ shallow,
                           const float* __restrict__ Wq, const float* __restrict__ bq,
                           const float* __restrict__ Wk, const float* __restrict__ bk,
                           uint16_t* __restrict__ Qb, uint16_t* __restrict__ Kb2) {
    int gid = blockIdx.x * 256 + threadIdx.x;   // 0..16383 = b*4096+n
    int b = gid >> 12;
    int n = gid & 4095;
    const float* sp = shallow + (size_t)b * 64 * 4096 + n;
    float q[16], k[16];
#pragma unroll
    for (int o = 0; o < 16; ++o) { q[o] = bq[o]; k[o] = bk[o]; }
    for (int c = 0; c < 64; ++c) {
        float s = sp[(size_t)c * 4096];
#pragma unroll
        for (int o = 0; o < 16; ++o) {
            q[o] = fmaf(Wq[o * 64 + c], s, q[o]);
            k[o] = fmaf(Wk[o * 64 + c], s, k[o]);
        }
    }
    uint16_t* qr = Qb + (size_t)gid * 32;
    float klo[16];
#pragma unroll
    for (int o = 0; o < 16; ++o) {
        __bf16 qh = (__bf16)q[o]; float qhf = (float)qh;
        __bf16 ql = (__bf16)(q[o] - qhf);
        qr[o]      = __builtin_bit_cast(uint16_t, qh);
        qr[16 + o] = __builtin_bit_cast(uint16_t, ql);
        klo[o] = k[o] - (float)((__bf16)k[o]);
    }
    uint16_t* kbase = Kb2 + (size_t)b * 131072 + (size_t)(n >> 5) * 1024
                          + (size_t)(n & 31) * 8;
    *(uint4*)(kbase +   0) = make_uint4(pack_bf2(k[0], k[1]),  pack_bf2(k[2], k[3]),
                                        pack_bf2(k[4], k[5]),  pack_bf2(k[6], k[7]));
    *(uint4*)(kbase + 256) = make_uint4(pack_bf2(k[8], k[9]),  pack_bf2(k[10], k[11]),
                                        pack_bf2(k[12], k[13]), pack_bf2(k[14], k[15]));
    *(uint4*)(kbase + 512) = make_uint4(pack_bf2(klo[0], klo[1]),  pack_bf2(klo[2], klo[3]),
                                        pack_bf2(klo[4], klo[5]),  pack_bf2(klo[6], klo[7]));
    *(uint4*)(kbase + 768) = make_uint4(pack_bf2(klo[8], klo[9]),  pack_bf2(klo[10], klo[11]),
                                        pack_bf2(klo[12], klo[13]), pack_bf2(klo[14], klo[15]));
}

// ---------------- Prepass 2: deep fp32 -> pre-swizzled bf16 V ------------
// V unit (16 B = 8 keys x 1 chan): gid = ((((b*8+ct)*256+kb)*2+h1)*32+c
//   stores deep[b][ct*32+c][kb*16+h1*8 .. +7].  attn phase-2 wave-load of
//   unit block (kb fixed, h1 x c = 64 lanes) is 1 KB contiguous.
__global__ void vconv(const float* __restrict__ deep, uint16_t* __restrict__ vb) {
    int gid = blockIdx.x * 256 + threadIdx.x;   // 0..524287
    int c  = gid & 31;
    int h1 = (gid >> 5) & 1;
    int kb = (gid >> 6) & 255;
    int ct = (gid >> 14) & 7;
    int b  = gid >> 17;
    int chan = ct * 32 + c;
    int key  = kb * 16 + h1 * 8;
    const float4* dp = (const float4*)(deep + ((size_t)(b * 256 + chan) * 4096 + key));
    float4 f0 = dp[0], f1 = dp[1];
    ((uint4*)vb)[gid] = make_uint4(pack_bf2(f0.x, f0.y), pack_bf2(f0.z, f0.w),
                                   pack_bf2(f1.x, f1.y), pack_bf2(f1.z, f1.w));
}

// ---------------- Main fused flash-attention kernel ----------------------
// Grid: 256 blocks x 512 threads. Block = (b, 64-query tile), all 256 chans.
// Superstep = 256 keys, ONE barrier per superstep (parity double-buffer).
// Phase 1: wave w computes energy for its 32-key slice x 64 queries (dup=1),
//   unnormalized p = exp2(e*log2e) (no max tracking: |e*log2e| <= ~40, fp32
//   exponent range absorbs it), packs P to MFMA B-frags in LDS.
// Phase 2: wave w owns 32 channels; each coalesced V unit feeds 2 MFMAs.
__global__ void __launch_bounds__(512, 2) attn_main(
    const uint16_t* __restrict__ Qb, const uint16_t* __restrict__ Kb2,
    const uint16_t* __restrict__ Vb, const float* __restrict__ deep,
    const float* __restrict__ gamma, float* __restrict__ out) {
    const int lane = threadIdx.x & 63;
    const int w    = threadIdx.x >> 6;   // phase1: key-slice; phase2: chan-tile
    const int col  = lane & 31;
    const int h1   = lane >> 5;

    // XCD-locality: one batch per XCD pair (V slice 2 MB < 4 MB L2/XCD).
    const int bid = blockIdx.x;
    const int xcd = bid & 7;
    const int b   = xcd >> 1;
    const int qt  = ((bid >> 3) << 1) + (xcd & 1);   // 0..63
    const int n0q = qt * 64;

    __shared__ uint4 Pl[2][2][16][64];   // parity, q-half, key-frag, lane = 64 KB
    __shared__ float Ls[2][2][8][32];    // parity, q-half, wave, query   =  8 KB

    // Hoisted Q B-frags for both query halves
    uint4 ubqh[2], ubql[2];
#pragma unroll
    for (int qh = 0; qh < 2; ++qh) {
        const uint16_t* qrow = Qb + ((size_t)(b * 4096 + n0q + qh * 32 + col)) * 32;
        ubqh[qh] = *(const uint4*)(qrow + h1 * 8);
        ubql[qh] = *(const uint4*)(qrow + 16 + h1 * 8);
    }

    // Per-lane bases for swizzled K and V
    const uint16_t* kbase = Kb2 + (size_t)b * 131072 + (size_t)w * 1024
                                + (size_t)lane * 8;                 // + ss*8192
    const uint16_t* vlane = Vb + (size_t)(b * 8 + w) * 131072
                               + (size_t)h1 * 256 + (size_t)col * 8; // + (ss*16+f)*512

    f32x16 acc0 = {0,0,0,0,0,0,0,0,0,0,0,0,0,0,0,0};
    f32x16 acc1 = {0,0,0,0,0,0,0,0,0,0,0,0,0,0,0,0};
    float l0 = 0.0f, l1 = 0.0f;

    // K prefetch for superstep 0
    uint4 ukh = *(const uint4*)(kbase);
    uint4 ukl = *(const uint4*)(kbase + 512);

    for (int ss = 0; ss < 16; ++ss) {
        const int par = ss & 1;

        // ---- phase 1: energy + unnormalized softmax for 32 keys x 64 q ----
        bf16x8 akh = __builtin_bit_cast(bf16x8, ukh);
        bf16x8 akl = __builtin_bit_cast(bf16x8, ukl);
#pragma unroll
        for (int qh = 0; qh < 2; ++qh) {
            bf16x8 bh = __builtin_bit_cast(bf16x8, ubqh[qh]);
            bf16x8 bl = __builtin_bit_cast(bf16x8, ubql[qh]);
            f32x16 e = {0,0,0,0,0,0,0,0,0,0,0,0,0,0,0,0};
            e = __builtin_amdgcn_mfma_f32_32x32x16_bf16(akh, bh, e, 0, 0, 0);
            e = __builtin_amdgcn_mfma_f32_32x32x16_bf16(akl, bh, e, 0, 0, 0);
            e = __builtin_amdgcn_mfma_f32_32x32x16_bf16(akh, bl, e, 0, 0, 0);

            float p[16];
#pragma unroll
            for (int r = 0; r < 16; ++r) p[r] = exp2f(e[r] * LOG2E);
            float t0 = (p[0] + p[1]) + (p[2] + p[3]);
            float t1 = (p[4] + p[5]) + (p[6] + p[7]);
            float t2 = (p[8] + p[9]) + (p[10] + p[11]);
            float t3 = (p[12] + p[13]) + (p[14] + p[15]);
            float ls = (t0 + t1) + (t2 + t3);
            ls += __shfl_xor(ls, 32, 64);
            if (lane < 32) Ls[par][qh][w][col] = ls;

            // pack P -> B-frags (C-layout key = (r&3)+8*(r>>2)+4*h1)
            uint32_t pk0 = pack_bf2(p[0],  p[1]),  pk1 = pack_bf2(p[2],  p[3]);
            uint32_t pk2 = pack_bf2(p[4],  p[5]),  pk3 = pack_bf2(p[6],  p[7]);
            uint32_t pk4 = pack_bf2(p[8],  p[9]),  pk5 = pack_bf2(p[10], p[11]);
            uint32_t pk6 = pack_bf2(p[12], p[13]), pk7 = pack_bf2(p[14], p[15]);
            uint32_t own_a = h1 ? pk2 : pk0, own_b = h1 ? pk3 : pk1;
            uint32_t cr_a  = h1 ? pk0 : pk2, cr_b  = h1 ? pk1 : pk3;
            uint32_t rc_a  = __shfl_xor(cr_a, 32, 64), rc_b = __shfl_xor(cr_b, 32, 64);
            uint4 f0u = make_uint4(h1 ? rc_a : own_a, h1 ? rc_b : own_b,
                                   h1 ? own_a : rc_a, h1 ? own_b : rc_b);
            uint32_t own_a1 = h1 ? pk6 : pk4, own_b1 = h1 ? pk7 : pk5;
            uint32_t cr_a1  = h1 ? pk4 : pk6, cr_b1  = h1 ? pk5 : pk7;
            uint32_t rc_a1  = __shfl_xor(cr_a1, 32, 64), rc_b1 = __shfl_xor(cr_b1, 32, 64);
            uint4 f1u = make_uint4(h1 ? rc_a1 : own_a1, h1 ? rc_b1 : own_b1,
                                   h1 ? own_a1 : rc_a1, h1 ? own_b1 : rc_b1);
            Pl[par][qh][w * 2 + 0][lane] = f0u;
            Pl[par][qh][w * 2 + 1][lane] = f1u;
        }
        __syncthreads();   // single barrier per superstep

        // ---- phase 2: K prefetch, l update, PV over 256 keys ----
        const int ssn = (ss < 15) ? ss + 1 : ss;
        ukh = *(const uint4*)(kbase + ssn * 8192);
        ukl = *(const uint4*)(kbase + ssn * 8192 + 512);

#pragma unroll
        for (int j = 0; j < 8; ++j) {
            l0 += Ls[par][0][j][col];
            l1 += Ls[par][1][j][col];
        }

        const uint16_t* vss = vlane + (size_t)ss * 8192;
#pragma unroll
        for (int f = 0; f < 16; ++f) {
            uint4 av  = *(const uint4*)(vss + f * 512);
            uint4 pb0 = Pl[par][0][f][lane];
            uint4 pb1 = Pl[par][1][f][lane];
            acc0 = __builtin_amdgcn_mfma_f32_32x32x16_bf16(
                __builtin_bit_cast(bf16x8, av), __builtin_bit_cast(bf16x8, pb0), acc0, 0, 0, 0);
            acc1 = __builtin_amdgcn_mfma_f32_32x32x16_bf16(
                __builtin_bit_cast(bf16x8, av), __builtin_bit_cast(bf16x8, pb1), acc1, 0, 0, 0);
        }
    }

    // ---- epilogue: out = gamma * acc/l + deep ----
    const float g   = gamma[0];
    const float gr0 = g / l0;
    const float gr1 = g / l1;
#pragma unroll
    for (int r = 0; r < 16; ++r) {
        const int crow = (r & 3) + 8 * (r >> 2) + 4 * h1;
        const int chan = w * 32 + crow;
        size_t i0 = (size_t)(b * 256 + chan) * 4096 + n0q + col;
        out[i0] = fmaf(gr0, acc0[r], deep[i0]);
        size_t i1 = i0 + 32;
        out[i1] = fmaf(gr1, acc1[r], deep[i1]);
    }
}

extern "C" void kernel_launch(void* const* d_in, const int* in_sizes, int n_in,
                              void* d_out, int out_size, void* d_ws, size_t ws_size,
                              hipStream_t stream) {
    const float* deep    = (const float*)d_in[0];
    const float* shallow = (const float*)d_in[1];
    const float* Wq      = (const float*)d_in[2];
    const float* bq      = (const float*)d_in[3];
    const float* Wk      = (const float*)d_in[4];
    const float* bk      = (const float*)d_in[5];
    const float* gamma   = (const float*)d_in[6];
    float* out = (float*)d_out;

    // ws layout: Vb swizzled bf16 (8 MiB) | Qb (1 MiB) | Kb2 (1 MiB)
    uint16_t* Vb  = (uint16_t*)d_ws;
    uint16_t* Qb  = (uint16_t*)((char*)d_ws + (size_t)8 * 1024 * 1024);
    uint16_t* Kb2 = (uint16_t*)((char*)d_ws + (size_t)9 * 1024 * 1024);

    hipLaunchKernelGGL(vconv, dim3(2048), dim3(256), 0, stream, deep, Vb);
    hipLaunchKernelGGL(qk_prepass, dim3(64), dim3(256), 0, stream,
                       shallow, Wq, bq, Wk, bk, Qb, Kb2);
    hipLaunchKernelGGL(attn_main, dim3(256), dim3(512), 0, stream,
                       Qb, Kb2, Vb, deep, gamma, out);
}

// Round 4
// 84.843 us; speedup vs baseline: 2.1344x; 1.2475x over previous
//
#include <hip/hip_runtime.h>
#include <hip/hip_bf16.h>
#include <stdint.h>

// Problem constants: B=4, deep_C=256, shallow_C=64, H=W=64, N=4096, qk_C=16.
#define LOG2E 1.44269504088896340736f

typedef __bf16 bf16x8 __attribute__((ext_vector_type(8)));
typedef float  f32x16 __attribute__((ext_vector_type(16)));

__device__ __forceinline__ uint32_t pack_bf2(float a, float b) {
    __bf16 ba = (__bf16)a;  // RNE
    __bf16 bb = (__bf16)b;
    uint16_t ua = __builtin_bit_cast(uint16_t, ba);
    uint16_t ub = __builtin_bit_cast(uint16_t, bb);
    return (uint32_t)ua | ((uint32_t)ub << 16);
}

// ---------------- Fused prepass: vconv (blocks 0..2047) + qk (2048..2111) ----
// Vb unit (16 B = 8 keys x 1 chan): gid = (((b*8+ct)*256+kb)*2+h1)*32+c
//   holds deep[b][ct*32+c][kb*16+h1*8 .. +7] as bf16.
// Qb rows: [b][n][32 bf16] = [hi c0..15 | lo c0..15], q PRE-SCALED by LOG2E.
// Kb2 units: addr_u16 = b*131072 + (n>>5)*1024 + s*512 + (h1*32+(n&31))*8,
//   s=0 hi / 1 lo  (a wave reads 1 KB contiguous per frag pair).
__global__ void __launch_bounds__(256) prepass(
    const float* __restrict__ deep, const float* __restrict__ shallow,
    const float* __restrict__ Wq, const float* __restrict__ bq,
    const float* __restrict__ Wk, const float* __restrict__ bk,
    uint16_t* __restrict__ Vb, uint16_t* __restrict__ Qb,
    uint16_t* __restrict__ Kb2) {
    const int blk = blockIdx.x;
    if (blk < 2048) {
        int gid = blk * 256 + threadIdx.x;   // 0..524287
        int c  = gid & 31;
        int h1 = (gid >> 5) & 1;
        int kb = (gid >> 6) & 255;
        int ct = (gid >> 14) & 7;
        int b  = gid >> 17;
        int chan = ct * 32 + c;
        int key  = kb * 16 + h1 * 8;
        const float4* dp = (const float4*)(deep + ((size_t)(b * 256 + chan) * 4096 + key));
        float4 f0 = dp[0], f1 = dp[1];
        ((uint4*)Vb)[gid] = make_uint4(pack_bf2(f0.x, f0.y), pack_bf2(f0.z, f0.w),
                                       pack_bf2(f1.x, f1.y), pack_bf2(f1.z, f1.w));
    } else {
        int gid = (blk - 2048) * 256 + threadIdx.x;  // 0..16383 = b*4096+n
        int b = gid >> 12;
        int n = gid & 4095;
        const float* sp = shallow + (size_t)b * 64 * 4096 + n;
        float q[16], k[16];
#pragma unroll
        for (int o = 0; o < 16; ++o) { q[o] = bq[o]; k[o] = bk[o]; }
        for (int c = 0; c < 64; ++c) {
            float s = sp[(size_t)c * 4096];
#pragma unroll
            for (int o = 0; o < 16; ++o) {
                q[o] = fmaf(Wq[o * 64 + c], s, q[o]);
                k[o] = fmaf(Wk[o * 64 + c], s, k[o]);
            }
        }
        uint16_t* qr = Qb + (size_t)gid * 32;
        float klo[16];
#pragma unroll
        for (int o = 0; o < 16; ++o) {
            float qs = q[o] * LOG2E;             // fold log2(e) into Q
            __bf16 qh = (__bf16)qs; float qhf = (float)qh;
            __bf16 ql = (__bf16)(qs - qhf);
            qr[o]      = __builtin_bit_cast(uint16_t, qh);
            qr[16 + o] = __builtin_bit_cast(uint16_t, ql);
            klo[o] = k[o] - (float)((__bf16)k[o]);
        }
        uint16_t* kbase = Kb2 + (size_t)b * 131072 + (size_t)(n >> 5) * 1024
                              + (size_t)(n & 31) * 8;
        *(uint4*)(kbase +   0) = make_uint4(pack_bf2(k[0], k[1]),   pack_bf2(k[2], k[3]),
                                            pack_bf2(k[4], k[5]),   pack_bf2(k[6], k[7]));
        *(uint4*)(kbase + 256) = make_uint4(pack_bf2(k[8], k[9]),   pack_bf2(k[10], k[11]),
                                            pack_bf2(k[12], k[13]), pack_bf2(k[14], k[15]));
        *(uint4*)(kbase + 512) = make_uint4(pack_bf2(klo[0], klo[1]),   pack_bf2(klo[2], klo[3]),
                                            pack_bf2(klo[4], klo[5]),   pack_bf2(klo[6], klo[7]));
        *(uint4*)(kbase + 768) = make_uint4(pack_bf2(klo[8], klo[9]),   pack_bf2(klo[10], klo[11]),
                                            pack_bf2(klo[12], klo[13]), pack_bf2(klo[14], klo[15]));
    }
}

// ---------------- Main fused flash-attention kernel ----------------------
// Grid: 256 blocks x 512 threads. Block = (b, 64-query tile), all 256 chans.
// Software-pipelined superstep (256 keys), ONE barrier per superstep:
//   iter ss: {issue V(ss) loads} | {QK+softmax(ss+1) -> Pl[par^1]} |
//            {PV(ss) from Pl[par]} | barrier.
// Softmax is max-free (|e| bounded; fp32 exponent absorbs exp2), P frags are
// assembled by direct transposed ds_write_b64 (no cross-lane shuffles).
__global__ void __launch_bounds__(512, 2) attn_main(
    const uint16_t* __restrict__ Qb, const uint16_t* __restrict__ Kb2,
    const uint16_t* __restrict__ Vb, const float* __restrict__ deep,
    const float* __restrict__ gamma, float* __restrict__ out) {
    const int lane = threadIdx.x & 63;
    const int w    = threadIdx.x >> 6;   // phase1: key-slice; phase2: chan-tile
    const int col  = lane & 31;
    const int h1   = lane >> 5;

    // XCD-locality: one batch per XCD pair (V slice 2 MB < 4 MB L2/XCD).
    const int bid = blockIdx.x;
    const int xcd = bid & 7;
    const int b   = xcd >> 1;
    const int qt  = ((bid >> 3) << 1) + (xcd & 1);   // 0..63
    const int n0q = qt * 64;

    __shared__ uint4 Pl[2][2][16][2][32];  // par, qh, frag, h1', col  = 64 KB
    __shared__ float Ls[2][2][16][32];     // par, qh, w*2+h1, col     =  8 KB

    // Hoisted Q B-frags for both query halves (pre-scaled by LOG2E)
    uint4 ubqh[2], ubql[2];
#pragma unroll
    for (int qh = 0; qh < 2; ++qh) {
        const uint16_t* qrow = Qb + ((size_t)(b * 4096 + n0q + qh * 32 + col)) * 32;
        ubqh[qh] = *(const uint4*)(qrow + h1 * 8);
        ubql[qh] = *(const uint4*)(qrow + 16 + h1 * 8);
    }

    const uint16_t* kbase = Kb2 + (size_t)b * 131072 + (size_t)w * 1024
                                + (size_t)lane * 8;                  // + ss*8192
    const uint16_t* vlane = Vb + (size_t)(b * 8 + w) * 131072
                               + (size_t)h1 * 256 + (size_t)col * 8; // + (ss*16+f)*512

    f32x16 acc0 = {0,0,0,0,0,0,0,0,0,0,0,0,0,0,0,0};
    f32x16 acc1 = {0,0,0,0,0,0,0,0,0,0,0,0,0,0,0,0};
    float l0 = 0.0f, l1 = 0.0f;

    uint4 ukh = *(const uint4*)(kbase);
    uint4 ukl = *(const uint4*)(kbase + 512);

    // QK + softmax for superstep s: writes Pl[s&1], Ls[s&1]; prefetches K(s+1).
    auto qk_softmax = [&](int s) {
        const int pr = s & 1;
        bf16x8 akh = __builtin_bit_cast(bf16x8, ukh);
        bf16x8 akl = __builtin_bit_cast(bf16x8, ukl);
        const int sn = (s < 15) ? s + 1 : s;
        uint4 nkh = *(const uint4*)(kbase + (size_t)sn * 8192);
        uint4 nkl = *(const uint4*)(kbase + (size_t)sn * 8192 + 512);
#pragma unroll
        for (int qh = 0; qh < 2; ++qh) {
            bf16x8 bh = __builtin_bit_cast(bf16x8, ubqh[qh]);
            bf16x8 bl = __builtin_bit_cast(bf16x8, ubql[qh]);
            f32x16 e = {0,0,0,0,0,0,0,0,0,0,0,0,0,0,0,0};
            e = __builtin_amdgcn_mfma_f32_32x32x16_bf16(akh, bh, e, 0, 0, 0);
            e = __builtin_amdgcn_mfma_f32_32x32x16_bf16(akl, bh, e, 0, 0, 0);
            e = __builtin_amdgcn_mfma_f32_32x32x16_bf16(akh, bl, e, 0, 0, 0);
            float p[16];
#pragma unroll
            for (int r = 0; r < 16; ++r) p[r] = exp2f(e[r]);  // already log2-scaled
            float t0 = (p[0] + p[1]) + (p[2] + p[3]);
            float t1 = (p[4] + p[5]) + (p[6] + p[7]);
            float t2 = (p[8] + p[9]) + (p[10] + p[11]);
            float t3 = (p[12] + p[13]) + (p[14] + p[15]);
            Ls[pr][qh][w * 2 + h1][col] = (t0 + t1) + (t2 + t3);  // per-half sum
            // direct transposed stores: B-frag[f][h1'][col] words 2h1..2h1+1
            uint32_t pk0 = pack_bf2(p[0],  p[1]),  pk1 = pack_bf2(p[2],  p[3]);
            uint32_t pk2 = pack_bf2(p[4],  p[5]),  pk3 = pack_bf2(p[6],  p[7]);
            uint32_t pk4 = pack_bf2(p[8],  p[9]),  pk5 = pack_bf2(p[10], p[11]);
            uint32_t pk6 = pack_bf2(p[12], p[13]), pk7 = pack_bf2(p[14], p[15]);
            ((uint2*)&Pl[pr][qh][2 * w    ][0][col])[h1] = make_uint2(pk0, pk1);
            ((uint2*)&Pl[pr][qh][2 * w    ][1][col])[h1] = make_uint2(pk2, pk3);
            ((uint2*)&Pl[pr][qh][2 * w + 1][0][col])[h1] = make_uint2(pk4, pk5);
            ((uint2*)&Pl[pr][qh][2 * w + 1][1][col])[h1] = make_uint2(pk6, pk7);
        }
        ukh = nkh; ukl = nkl;
    };

    qk_softmax(0);
    __syncthreads();

#pragma unroll 2
    for (int ss = 0; ss < 16; ++ss) {
        const int par = ss & 1;
        // issue-early V loads for this superstep (consumed after softmax)
        uint4 vr[16];
        const uint16_t* vss = vlane + (size_t)ss * 8192;
#pragma unroll
        for (int f = 0; f < 16; ++f) vr[f] = *(const uint4*)(vss + f * 512);

        if (ss < 15) qk_softmax(ss + 1);   // overlaps with PV below (no barrier)

        __builtin_amdgcn_s_setprio(1);
#pragma unroll
        for (int f = 0; f < 16; ++f) {
            uint4 pb0 = Pl[par][0][f][h1][col];
            uint4 pb1 = Pl[par][1][f][h1][col];
            acc0 = __builtin_amdgcn_mfma_f32_32x32x16_bf16(
                __builtin_bit_cast(bf16x8, vr[f]), __builtin_bit_cast(bf16x8, pb0), acc0, 0, 0, 0);
            acc1 = __builtin_amdgcn_mfma_f32_32x32x16_bf16(
                __builtin_bit_cast(bf16x8, vr[f]), __builtin_bit_cast(bf16x8, pb1), acc1, 0, 0, 0);
        }
        __builtin_amdgcn_s_setprio(0);

#pragma unroll
        for (int j = 0; j < 16; ++j) {
            l0 += Ls[par][0][j][col];
            l1 += Ls[par][1][j][col];
        }
        __syncthreads();
    }

    // ---- epilogue: out = gamma * acc/l + deep ----
    const float g   = gamma[0];
    const float gr0 = g / l0;
    const float gr1 = g / l1;
#pragma unroll
    for (int r = 0; r < 16; ++r) {
        const int crow = (r & 3) + 8 * (r >> 2) + 4 * h1;
        const int chan = w * 32 + crow;
        size_t i0 = (size_t)(b * 256 + chan) * 4096 + n0q + col;
        out[i0] = fmaf(gr0, acc0[r], deep[i0]);
        size_t i1 = i0 + 32;
        out[i1] = fmaf(gr1, acc1[r], deep[i1]);
    }
}

extern "C" void kernel_launch(void* const* d_in, const int* in_sizes, int n_in,
                              void* d_out, int out_size, void* d_ws, size_t ws_size,
                              hipStream_t stream) {
    const float* deep    = (const float*)d_in[0];
    const float* shallow = (const float*)d_in[1];
    const float* Wq      = (const float*)d_in[2];
    const float* bq      = (const float*)d_in[3];
    const float* Wk      = (const float*)d_in[4];
    const float* bk      = (const float*)d_in[5];
    const float* gamma   = (const float*)d_in[6];
    float* out = (float*)d_out;

    // ws layout: Vb swizzled bf16 (8 MiB) | Qb (1 MiB) | Kb2 (1 MiB)
    uint16_t* Vb  = (uint16_t*)d_ws;
    uint16_t* Qb  = (uint16_t*)((char*)d_ws + (size_t)8 * 1024 * 1024);
    uint16_t* Kb2 = (uint16_t*)((char*)d_ws + (size_t)9 * 1024 * 1024);

    hipLaunchKernelGGL(prepass, dim3(2112), dim3(256), 0, stream,
                       deep, shallow, Wq, bq, Wk, bk, Vb, Qb, Kb2);
    hipLaunchKernelGGL(attn_main, dim3(256), dim3(512), 0, stream,
                       Qb, Kb2, Vb, deep, gamma, out);
}